// Round 4
// baseline (2113.602 us; speedup 1.0000x reference)
//
#include <hip/hip_runtime.h>

#define BB 64
#define PP 10000
#define EE 128
#define CC 100
#define PLANE (CC * 32)        // 3200 floats per component-plane
#define ROWS  (CC * EE)        // 12800 floats = full [C][E]

typedef float v4f __attribute__((ext_vector_type(4)));

// ---------------------------------------------------------------------------
// Fused kernel: one block per batch.
//   Phase 1: segment-sum of the batch's 10000 rows into a planar LDS
//            accumulator ([4][CC][32]: element e of cluster c at
//            (e&3)*PLANE + c*32 + (e>>2) -> ds bank == lane, conflict-free).
//   Phase 2: counts -> 1/max(cnt,1).
//   Phase 3: mean + Linear(E,E) in 13 groups of 8 clusters: means staged
//            transposed in s_mt[k][8] (wave-uniform float4 broadcast reads);
//            each thread streams its own 512-B W row (L1-resident across
//            passes). Writes ce directly.
// Eliminates the psums round-trip (104 MB of fabric traffic) and the
// separate project kernel.
// ---------------------------------------------------------------------------
__global__ __launch_bounds__(256) void fused_kernel(
    const float* __restrict__ nodes, const int* __restrict__ ids,
    const float* __restrict__ W, const float* __restrict__ bias,
    float* __restrict__ ce)
{
    __shared__ float s_acc[ROWS];     // 51200 B, planar [4][CC][32]
    __shared__ float s_cnt[CC];
    __shared__ float s_inv[CC];
    __shared__ float s_mt[EE * 8];    // 4096 B: s_mt[k*8+rr] = mean[c0+rr][k]

    const int tid = threadIdx.x;
    const int b   = blockIdx.x;

    for (int i = tid; i < ROWS; i += 256) s_acc[i] = 0.f;
    if (tid < CC) s_cnt[tid] = 0.f;
    __syncthreads();

    // ---- Phase 1: scatter-accumulate --------------------------------------
    const int lane = tid & 31;        // float4 slot within a row
    const int sub  = tid >> 5;        // 8 rows in flight per block step
    const v4f* src = (const v4f*)(nodes + (size_t)b * PP * EE);
    const int* idb = ids + b * PP;

#pragma unroll 4
    for (int p = sub; p < PP; p += 8) {
        int c = idb[p];                            // 32 lanes broadcast, L1
        v4f v = src[(size_t)p * 32 + lane];        // 512 B contiguous/group
        if ((unsigned)c < CC) {
            float* a = &s_acc[c * 32 + lane];
            __hip_atomic_fetch_add(a + 0 * PLANE, v.x, __ATOMIC_RELAXED, __HIP_MEMORY_SCOPE_WORKGROUP);
            __hip_atomic_fetch_add(a + 1 * PLANE, v.y, __ATOMIC_RELAXED, __HIP_MEMORY_SCOPE_WORKGROUP);
            __hip_atomic_fetch_add(a + 2 * PLANE, v.z, __ATOMIC_RELAXED, __HIP_MEMORY_SCOPE_WORKGROUP);
            __hip_atomic_fetch_add(a + 3 * PLANE, v.w, __ATOMIC_RELAXED, __HIP_MEMORY_SCOPE_WORKGROUP);
            if (lane == 0)
                __hip_atomic_fetch_add(&s_cnt[c], 1.0f, __ATOMIC_RELAXED, __HIP_MEMORY_SCOPE_WORKGROUP);
        }
    }
    __syncthreads();

    // ---- Phase 2: inverse counts ------------------------------------------
    if (tid < CC) s_inv[tid] = 1.0f / fmaxf(s_cnt[tid], 1.0f);

    // ---- Phase 3: mean + Linear(E,E), 13 groups of 8 clusters -------------
    const int e    = tid & 127;
    const int sub2 = tid >> 7;                     // 0..1, wave-uniform
    const float be = bias[e];
    const float* __restrict__ wrow = W + (size_t)e * EE;  // thread's W row
    float* ceb = ce + (size_t)b * CC * EE;

    for (int g = 0; g < 13; ++g) {
        __syncthreads();   // s_inv ready (g=0) / s_mt consumed (g>0)
        for (int i = tid; i < 8 * EE; i += 256) {
            int rr = i >> 7, k = i & 127;
            int c = g * 8 + rr;
            float m = 0.f;
            if (c < CC)
                m = s_acc[(k & 3) * PLANE + c * 32 + (k >> 2)] * s_inv[c];
            s_mt[k * 8 + rr] = m;
        }
        __syncthreads();

        float acc0 = 0.f, acc1 = 0.f, acc2 = 0.f, acc3 = 0.f;
        const v4f* mp = (const v4f*)s_mt;  // mp[k*2+sub2] = mean[c0..c0+3][k]
#pragma unroll 8
        for (int k = 0; k < 128; ++k) {
            float w = wrow[k];             // per-thread sequential, L1-hot
            v4f   m = mp[k * 2 + sub2];    // wave-uniform broadcast b128
            acc0 = fmaf(w, m.x, acc0);
            acc1 = fmaf(w, m.y, acc1);
            acc2 = fmaf(w, m.z, acc2);
            acc3 = fmaf(w, m.w, acc3);
        }
        const int c0 = g * 8 + sub2 * 4;
        if (c0 + 0 < CC) ceb[(size_t)(c0 + 0) * EE + e] = be + acc0;
        if (c0 + 1 < CC) ceb[(size_t)(c0 + 1) * EE + e] = be + acc1;
        if (c0 + 2 < CC) ceb[(size_t)(c0 + 2) * EE + e] = be + acc2;
        if (c0 + 3 < CC) ceb[(size_t)(c0 + 3) * EE + e] = be + acc3;
    }
}

// ---------------------------------------------------------------------------
// Gather: read ce (L2-resident) directly, nontemporal-store gn (write-once,
// keep it from thrashing L3 so nodes stays partially resident for the next
// iteration's scatter).
// ---------------------------------------------------------------------------
__global__ __launch_bounds__(256) void gather_kernel(
    const int* __restrict__ ids, const float* __restrict__ ce,
    float* __restrict__ gn)
{
    const int tid  = threadIdx.x;
    const int lane = tid & 31;
    const int sub  = tid >> 5;
    const int b    = blockIdx.y;

    const int* idb = ids + b * PP;
    const v4f* ceb = (const v4f*)(ce + (size_t)b * CC * EE);
    v4f* dst = (v4f*)(gn + (size_t)b * PP * EE);

#pragma unroll 2
    for (int p = blockIdx.x * 8 + sub; p < PP; p += 32 * 8) {
        int c = idb[p];
        if ((unsigned)c >= CC) c = 0;   // safety (never taken)
        v4f v = ceb[(size_t)c * 32 + lane];
        __builtin_nontemporal_store(v, &dst[(size_t)p * 32 + lane]);
    }
}

extern "C" void kernel_launch(void* const* d_in, const int* in_sizes, int n_in,
                              void* d_out, int out_size, void* d_ws, size_t ws_size,
                              hipStream_t stream)
{
    const float* nodes = (const float*)d_in[0];
    const int*   ids   = (const int*)d_in[1];
    // d_in[2] = num_clusters (scalar, fixed at 100 — compile-time here)
    const float* W     = (const float*)d_in[3];
    const float* bias  = (const float*)d_in[4];

    float* out = (float*)d_out;
    float* ce  = out;                               // [64][100][128]
    float* gn  = out + (size_t)BB * CC * EE;        // [64][10000][128]

    hipLaunchKernelGGL(fused_kernel, dim3(BB), dim3(256), 0, stream,
                       nodes, ids, W, bias, ce);
    hipLaunchKernelGGL(gather_kernel, dim3(32, BB), dim3(256), 0, stream,
                       ids, ce, gn);
}